// Round 21
// baseline (411.067 us; speedup 1.0000x reference)
//
#include <hip/hip_runtime.h>
#include <stdint.h>
#include <math.h>

// Multiresolution hash encoding, 16 levels — single persistent kernel, global
// work queue (normal launch; deadlock-free by queue-grab ordering).
//   works [0,512):     pool bands (levels 0..12, 8 image rows, R16 body)
//   works [512,1536):  levels 13..15 direct (kh=1, identity bilinear)
//   works [1536,4864): 64x64 tiles (levels 0..12), batch-major; POLITE gate:
//                      relaxed poll + one acquire fence (no L2-invalidate storm).

#define NLVL 16
#define NB   16

__constant__ int   c_P[NLVL]   = {4,5,6,9,12,15,21,28,36,51,64,85,128,256,256,256};
__constant__ float c_G[NLVL]   = {4.f,5.f,6.f,9.f,12.f,15.f,21.f,27.f,36.f,48.f,63.f,84.f,111.f,147.f,194.f,255.f};
__constant__ int   c_CUM[14]   = {0,16,41,77,158,302,527,968,1752,3048,5649,9745,16970,33354};

#define CELLS_PB    33354
#define CELLS_TOT   (CELLS_PB*NB)        // 533664
#define MWS_FLOATS  (CELLS_TOT*3)        // 1600992
#define POOL_WORKS  512
#define DIR_WORKS   1024
#define TILE_WORKS  (13*16*16)           // 3328
#define TOTAL_WORKS (POOL_WORKS + DIR_WORKS + TILE_WORKS)   // 4864
#define GRID_BLOCKS 1024

__device__ __forceinline__ uint32_t hash3(float m0, float m1, float m2, float g) {
    uint32_t v0 = (uint32_t)(int)(m0 * g);
    uint32_t v1 = (uint32_t)(int)(m1 * g);
    uint32_t v2 = (uint32_t)(int)(m2 * g);
    return (v0 ^ (v1 * 2654435761u) ^ (v2 * 805459861u)) & 0xFFFFu;
}

__global__ __launch_bounds__(256, 4) void mega(const float* __restrict__ img,
                                               const float* __restrict__ tab,
                                               float* __restrict__ mws,
                                               unsigned int* __restrict__ ctrs,
                                               float* __restrict__ out)
{
    static constexpr int K_P[13]   = {4,5,6,9,12,15,21,28,36,51,64,85,128};
    static constexpr int K_KH[13]  = {64,51,42,28,21,17,12,9,7,5,4,3,2};
    static constexpr int K_CUM[13] = {0,16,41,77,158,302,527,968,1752,3048,5649,9745,16970};

    __shared__ __align__(16) char smem[27648];   // union: pool 27648 B / tile 18496 B
    __shared__ unsigned int s_w;

    unsigned int* q    = ctrs;       // work queue head
    unsigned int* bctr = ctrs + 1;   // per-batch completed-band counters [16]

    for (;;) {
        __syncthreads();
        if (threadIdx.x == 0) s_w = atomicAdd(q, 1u);
        __syncthreads();
        unsigned int w = s_w;
        if (w >= TOTAL_WORKS) return;

        if (w < POOL_WORKS) {
            // ---- pool band: batch b, 8-row band (R16 body) ----
            float (*simg)[8][256] = (float(*)[8][256])smem;
            float (*colbuf)[256]  = (float(*)[256])(smem + 24576);
            int b    = w >> 5;
            int band = w & 31;
            int y0   = band * 8;

            const float* base = img + (size_t)b * 196608 + (size_t)y0 * 256;
            for (int t = threadIdx.x; t < 1536; t += 256) {
                int ch = t >> 9;
                int r  = t & 511;
                float4 v = *(const float4*)(base + (size_t)ch * 65536 + r * 4);
                int row = r >> 6, c4 = (r & 63) << 2;
                simg[ch][row][c4 + 0] = v.x;
                simg[ch][row][c4 + 1] = v.y;
                simg[ch][row][c4 + 2] = v.z;
                simg[ch][row][c4 + 3] = v.w;
            }
            __syncthreads();

            int x = threadIdx.x;
#pragma unroll
            for (int lvl = 0; lvl < 13; ++lvl) {
                const int kh = K_KH[lvl], P = K_P[lvl];
                int nr0 = y0 / kh;
                int nr1 = (y0 + 7) / kh; if (nr1 > P - 1) nr1 = P - 1;
                for (int cr = nr0; cr <= nr1; ++cr) {
                    int rlo = cr * kh;      if (rlo < y0) rlo = y0;
                    int rhi = cr * kh + kh; if (rhi > y0 + 8) rhi = y0 + 8;
                    float p0 = -INFINITY, p1 = -INFINITY, p2 = -INFINITY;
                    for (int r = rlo; r < rhi; ++r) {
                        int rr = r - y0;
                        p0 = fmaxf(p0, simg[0][rr][x]);
                        p1 = fmaxf(p1, simg[1][rr][x]);
                        p2 = fmaxf(p2, simg[2][rr][x]);
                    }
                    colbuf[0][x] = p0; colbuf[1][x] = p1; colbuf[2][x] = p2;
                    __syncthreads();
                    if (x < P) {
                        float q0 = -INFINITY, q1 = -INFINITY, q2 = -INFINITY;
                        for (int c = x * kh; c < x * kh + kh; ++c) {
                            q0 = fmaxf(q0, colbuf[0][c]);
                            q1 = fmaxf(q1, colbuf[1][c]);
                            q2 = fmaxf(q2, colbuf[2][c]);
                        }
                        int idx = K_CUM[lvl] * NB + b * P * P + cr * P + x;
                        if (rlo == cr * kh && rhi == cr * kh + kh) {
                            mws[idx]                 = q0;
                            mws[idx + CELLS_TOT]     = q1;
                            mws[idx + 2 * CELLS_TOT] = q2;
                        } else {
                            atomicMax((unsigned int*)&mws[idx],                 __float_as_uint(q0));
                            atomicMax((unsigned int*)&mws[idx + CELLS_TOT],     __float_as_uint(q1));
                            atomicMax((unsigned int*)&mws[idx + 2 * CELLS_TOT], __float_as_uint(q2));
                        }
                    }
                    __syncthreads();
                }
            }
            __threadfence();            // flush this band's maxima to coherence point
            __syncthreads();
            if (threadIdx.x == 0)
                __hip_atomic_fetch_add(&bctr[b], 1u, __ATOMIC_RELEASE, __HIP_MEMORY_SCOPE_AGENT);
        } else if (w < POOL_WORKS + DIR_WORKS) {
            // ---- direct: levels 13..15, identity bilinear, 4 px/thread ----
            int t = (int)(w - POOL_WORKS) * 256 + threadIdx.x;   // 262144 total
            int b = t >> 14;
            int pix0 = (t & 16383) << 2;
            const float* p = img + (size_t)b * 196608 + pix0;
            float4 i0 = *(const float4*)p;
            float4 i1 = *(const float4*)(p + 65536);
            float4 i2 = *(const float4*)(p + 131072);
#pragma unroll
            for (int lvl = 13; lvl < 16; ++lvl) {
                float g = c_G[lvl];
                const float* T = tab + (size_t)lvl * 196608;
                uint32_t g0 = hash3(i0.x, i1.x, i2.x, g);
                uint32_t g1 = hash3(i0.y, i1.y, i2.y, g);
                uint32_t g2 = hash3(i0.z, i1.z, i2.z, g);
                uint32_t g3 = hash3(i0.w, i1.w, i2.w, g);
                float3 f0 = *(const float3*)(T + g0 * 3);
                float3 f1 = *(const float3*)(T + g1 * 3);
                float3 f2 = *(const float3*)(T + g2 * 3);
                float3 f3 = *(const float3*)(T + g3 * 3);
                float4 o0, o1, o2;
                o0.x = f0.x; o1.x = f0.y; o2.x = f0.z;
                o0.y = f1.x; o1.y = f1.y; o2.y = f1.z;
                o0.z = f2.x; o1.z = f2.y; o2.z = f2.z;
                o0.w = f3.x; o1.w = f3.y; o2.w = f3.z;
                float* ob = out + ((size_t)b * 48 + 3 * lvl) * 65536 + pix0;
                *(float4*)ob            = o0;
                *(float4*)(ob + 65536)  = o1;
                *(float4*)(ob + 131072) = o2;
            }
        } else {
            // ---- tile: levels 0..12, batch-major order ----
            float4* s = (float4*)smem;
            int tw   = (int)(w - POOL_WORKS - DIR_WORKS);   // 0..3327
            int b    = tw / 208;
            int r208 = tw - b * 208;
            int lvl  = r208 >> 4;
            int tile = r208 & 15;
            int P    = c_P[lvl];
            int yt0  = (tile >> 2) * 64;
            int xt0  = (tile & 3) * 64;

            // POLITE gate: relaxed poll (no invalidation), one acquire fence after.
            if (threadIdx.x == 0) {
                while (__hip_atomic_load(&bctr[b], __ATOMIC_RELAXED, __HIP_MEMORY_SCOPE_AGENT) < 32u)
                    __builtin_amdgcn_s_sleep(8);
                __builtin_amdgcn_fence(__ATOMIC_ACQUIRE, "agent");
            }
            __syncthreads();

            int nlo  = ((2 * yt0 + 1) * P - 256) >> 9;
            int r_lo = nlo < 0 ? 0 : (nlo > P - 1 ? P - 1 : nlo);
            int nhi  = (((2 * (yt0 + 63) + 1) * P - 256) >> 9) + 1;
            int r_hi = nhi < 0 ? 0 : (nhi > P - 1 ? P - 1 : nhi);
            int mlo  = ((2 * xt0 + 1) * P - 256) >> 9;
            int c_lo = mlo < 0 ? 0 : (mlo > P - 1 ? P - 1 : mlo);
            int mhi  = (((2 * (xt0 + 63) + 1) * P - 256) >> 9) + 1;
            int c_hi = mhi < 0 ? 0 : (mhi > P - 1 ? P - 1 : mhi);
            int span_y = r_hi - r_lo + 1;
            int span_x = c_hi - c_lo + 1;

            int planebase = c_CUM[lvl] * NB + b * P * P;
            const float* T = tab + (size_t)lvl * 196608;
            float gmul = c_G[lvl];
            int n = span_y * span_x;
            for (int t = threadIdx.x; t < n; t += 256) {
                int rr = t / span_x, cc = t - rr * span_x;
                int idx = planebase + (r_lo + rr) * P + c_lo + cc;
                float m0 = mws[idx];
                float m1 = mws[idx + CELLS_TOT];
                float m2 = mws[idx + 2 * CELLS_TOT];
                uint32_t g = hash3(m0, m1, m2, gmul);
                float3 tv = *(const float3*)(T + g * 3);
                float4 fv; fv.x = tv.x; fv.y = tv.y; fv.z = tv.z; fv.w = 0.f;
                s[t] = fv;
            }
            __syncthreads();

            int lane = threadIdx.x & 63;
            int wv   = threadIdx.x >> 6;
            int xq   = lane & 15;
            int rg   = lane >> 4;
            int xb   = xt0 + xq * 4;

            int ix0t[4], ix1t[4]; float wx0t[4], wx1t[4];
#pragma unroll
            for (int j = 0; j < 4; ++j) {
                int numx = (2 * (xb + j) + 1) * P - 256;
                int ix0  = numx >> 9;
                float fx = (float)(numx & 511) * (1.0f / 512.0f);
                int ix1;
                if (ix0 < 0)           { ix0 = 0;     ix1 = 0;     fx = 0.f; }
                else if (ix0 >= P - 1) { ix0 = P - 1; ix1 = P - 1; fx = 0.f; }
                else                   { ix1 = ix0 + 1; }
                ix0t[j] = ix0 - c_lo; ix1t[j] = ix1 - c_lo; wx1t[j] = fx; wx0t[j] = 1.f - fx;
            }

            int cur0 = -1, cur1 = -1;
            float r0v[3][4], r1v[3][4];

#pragma unroll
            for (int k = 0; k < 4; ++k) {
                int y = yt0 + wv * 16 + rg * 4 + k;
                int numy = (2 * y + 1) * P - 256;
                int iy0  = numy >> 9;
                float fy = (float)(numy & 511) * (1.0f / 512.0f);
                int iy1;
                if (iy0 < 0)           { iy0 = 0;     iy1 = 0;     fy = 0.f; }
                else if (iy0 >= P - 1) { iy0 = P - 1; iy1 = P - 1; fy = 0.f; }
                else                   { iy1 = iy0 + 1; }

                if (iy0 != cur0) {
                    if (iy0 == cur1) {
#pragma unroll
                        for (int j = 0; j < 4; ++j) {
                            r0v[0][j] = r1v[0][j]; r0v[1][j] = r1v[1][j]; r0v[2][j] = r1v[2][j];
                        }
                    } else {
                        const float4* p0 = s + (iy0 - r_lo) * span_x;
#pragma unroll
                        for (int j = 0; j < 4; ++j) {
                            float4 a = p0[ix0t[j]], qq = p0[ix1t[j]];
                            r0v[0][j] = wx0t[j] * a.x + wx1t[j] * qq.x;
                            r0v[1][j] = wx0t[j] * a.y + wx1t[j] * qq.y;
                            r0v[2][j] = wx0t[j] * a.z + wx1t[j] * qq.z;
                        }
                    }
                    cur0 = iy0;
                }
                if (iy1 != cur1) {
                    if (iy1 == cur0 && iy1 == iy0) {
#pragma unroll
                        for (int j = 0; j < 4; ++j) {
                            r1v[0][j] = r0v[0][j]; r1v[1][j] = r0v[1][j]; r1v[2][j] = r0v[2][j];
                        }
                    } else {
                        const float4* p1 = s + (iy1 - r_lo) * span_x;
#pragma unroll
                        for (int j = 0; j < 4; ++j) {
                            float4 a = p1[ix0t[j]], qq = p1[ix1t[j]];
                            r1v[0][j] = wx0t[j] * a.x + wx1t[j] * qq.x;
                            r1v[1][j] = wx0t[j] * a.y + wx1t[j] * qq.y;
                            r1v[2][j] = wx0t[j] * a.z + wx1t[j] * qq.z;
                        }
                    }
                    cur1 = iy1;
                }

                float wy1 = fy, wy0 = 1.f - fy;
                float* o = out + ((size_t)b * 48 + 3 * lvl) * 65536 + (size_t)y * 256 + xb;
#pragma unroll
                for (int c = 0; c < 3; ++c) {
                    float4 qv;
                    qv.x = wy0 * r0v[c][0] + wy1 * r1v[c][0];
                    qv.y = wy0 * r0v[c][1] + wy1 * r1v[c][1];
                    qv.z = wy0 * r0v[c][2] + wy1 * r1v[c][2];
                    qv.w = wy0 * r0v[c][3] + wy1 * r1v[c][3];
                    *(float4*)(o + (size_t)c * 65536) = qv;
                }
            }
        }
    }
}

extern "C" void kernel_launch(void* const* d_in, const int* in_sizes, int n_in,
                              void* d_out, int out_size, void* d_ws, size_t ws_size,
                              hipStream_t stream)
{
    const float* img = (const float*)d_in[0];   // (16,3,256,256) f32
    const float* tab = (const float*)d_in[1];   // (16,65536,3) f32
    float* out = (float*)d_out;                 // (16,48,256,256) f32
    float* mws = (float*)d_ws;                  // 6.4 MB maxima
    unsigned int* ctrs = (unsigned int*)((char*)d_ws + (size_t)MWS_FLOATS * 4);

    (void)hipMemsetAsync(mws, 0, (size_t)MWS_FLOATS * 4, stream);   // straddle cells use atomicMax
    (void)hipMemsetAsync(ctrs, 0, 128, stream);                     // queue head + 16 batch counters

    hipLaunchKernelGGL(mega, dim3(GRID_BLOCKS), dim3(256), 0, stream,
                       img, tab, mws, ctrs, out);
}

// Round 22
// 218.685 us; speedup vs baseline: 1.8797x; 1.8797x over previous
//
#include <hip/hip_runtime.h>
#include <stdint.h>
#include <math.h>

// Multiresolution hash encoding, 16 levels — single fused kernel, STATIC work
// striding (no work queue): grid 1280 co-resident blocks, block i handles
// works {i, i+1280, ...}. Works: [0,512) pool bands (R16 body), [512,1536)
// levels 13..15 direct, [1536,4864) 64x64 tiles (batch-major) gated on the
// batch's 32 pool bands via relaxed poll + one acquire fence.
// Deadlock-free: every block's FIRST work never waits (w < 1280), so all pool
// works run on co-resident blocks; tiles are only second+ works.

#define NLVL 16
#define NB   16

__constant__ int   c_P[NLVL]   = {4,5,6,9,12,15,21,28,36,51,64,85,128,256,256,256};
__constant__ float c_G[NLVL]   = {4.f,5.f,6.f,9.f,12.f,15.f,21.f,27.f,36.f,48.f,63.f,84.f,111.f,147.f,194.f,255.f};
__constant__ int   c_CUM[14]   = {0,16,41,77,158,302,527,968,1752,3048,5649,9745,16970,33354};

#define CELLS_PB    33354
#define CELLS_TOT   (CELLS_PB*NB)        // 533664
#define MWS_FLOATS  (CELLS_TOT*3)        // 1600992
#define POOL_WORKS  512
#define DIR_WORKS   1024
#define TILE_WORKS  (13*16*16)           // 3328
#define TOTAL_WORKS (POOL_WORKS + DIR_WORKS + TILE_WORKS)   // 4864
#define GRID_BLOCKS 1280                 // 5 blocks/CU co-resident (27.6 KB LDS)

__device__ __forceinline__ uint32_t hash3(float m0, float m1, float m2, float g) {
    uint32_t v0 = (uint32_t)(int)(m0 * g);
    uint32_t v1 = (uint32_t)(int)(m1 * g);
    uint32_t v2 = (uint32_t)(int)(m2 * g);
    return (v0 ^ (v1 * 2654435761u) ^ (v2 * 805459861u)) & 0xFFFFu;
}

__global__ __launch_bounds__(256, 5) void mega(const float* __restrict__ img,
                                               const float* __restrict__ tab,
                                               float* __restrict__ mws,
                                               unsigned int* __restrict__ bctr,
                                               float* __restrict__ out)
{
    static constexpr int K_P[13]   = {4,5,6,9,12,15,21,28,36,51,64,85,128};
    static constexpr int K_KH[13]  = {64,51,42,28,21,17,12,9,7,5,4,3,2};
    static constexpr int K_CUM[13] = {0,16,41,77,158,302,527,968,1752,3048,5649,9745,16970};

    __shared__ __align__(16) char smem[27648];   // union: pool 27648 B / tile 18496 B

    for (unsigned int w = blockIdx.x; w < TOTAL_WORKS; w += GRID_BLOCKS) {
        __syncthreads();                          // guard LDS reuse across works

        if (w < POOL_WORKS) {
            // ---- pool band: batch b, 8-row band (R16 body) ----
            float (*simg)[8][256] = (float(*)[8][256])smem;
            float (*colbuf)[256]  = (float(*)[256])(smem + 24576);
            int b    = w >> 5;
            int band = w & 31;
            int y0   = band * 8;

            const float* base = img + (size_t)b * 196608 + (size_t)y0 * 256;
            for (int t = threadIdx.x; t < 1536; t += 256) {
                int ch = t >> 9;
                int r  = t & 511;
                float4 v = *(const float4*)(base + (size_t)ch * 65536 + r * 4);
                int row = r >> 6, c4 = (r & 63) << 2;
                simg[ch][row][c4 + 0] = v.x;
                simg[ch][row][c4 + 1] = v.y;
                simg[ch][row][c4 + 2] = v.z;
                simg[ch][row][c4 + 3] = v.w;
            }
            __syncthreads();

            int x = threadIdx.x;
#pragma unroll
            for (int lvl = 0; lvl < 13; ++lvl) {
                const int kh = K_KH[lvl], P = K_P[lvl];
                int nr0 = y0 / kh;
                int nr1 = (y0 + 7) / kh; if (nr1 > P - 1) nr1 = P - 1;
                for (int cr = nr0; cr <= nr1; ++cr) {
                    int rlo = cr * kh;      if (rlo < y0) rlo = y0;
                    int rhi = cr * kh + kh; if (rhi > y0 + 8) rhi = y0 + 8;
                    float p0 = -INFINITY, p1 = -INFINITY, p2 = -INFINITY;
                    for (int r = rlo; r < rhi; ++r) {
                        int rr = r - y0;
                        p0 = fmaxf(p0, simg[0][rr][x]);
                        p1 = fmaxf(p1, simg[1][rr][x]);
                        p2 = fmaxf(p2, simg[2][rr][x]);
                    }
                    colbuf[0][x] = p0; colbuf[1][x] = p1; colbuf[2][x] = p2;
                    __syncthreads();
                    if (x < P) {
                        float q0 = -INFINITY, q1 = -INFINITY, q2 = -INFINITY;
                        for (int c = x * kh; c < x * kh + kh; ++c) {
                            q0 = fmaxf(q0, colbuf[0][c]);
                            q1 = fmaxf(q1, colbuf[1][c]);
                            q2 = fmaxf(q2, colbuf[2][c]);
                        }
                        int idx = K_CUM[lvl] * NB + b * P * P + cr * P + x;
                        if (rlo == cr * kh && rhi == cr * kh + kh) {
                            mws[idx]                 = q0;
                            mws[idx + CELLS_TOT]     = q1;
                            mws[idx + 2 * CELLS_TOT] = q2;
                        } else {
                            atomicMax((unsigned int*)&mws[idx],                 __float_as_uint(q0));
                            atomicMax((unsigned int*)&mws[idx + CELLS_TOT],     __float_as_uint(q1));
                            atomicMax((unsigned int*)&mws[idx + 2 * CELLS_TOT], __float_as_uint(q2));
                        }
                    }
                    __syncthreads();
                }
            }
            __threadfence();            // flush this band's maxima to coherence point
            __syncthreads();
            if (threadIdx.x == 0)
                __hip_atomic_fetch_add(&bctr[b], 1u, __ATOMIC_RELEASE, __HIP_MEMORY_SCOPE_AGENT);
        } else if (w < POOL_WORKS + DIR_WORKS) {
            // ---- direct: levels 13..15, identity bilinear, 4 px/thread ----
            int t = (int)(w - POOL_WORKS) * 256 + threadIdx.x;   // 262144 total
            int b = t >> 14;
            int pix0 = (t & 16383) << 2;
            const float* p = img + (size_t)b * 196608 + pix0;
            float4 i0 = *(const float4*)p;
            float4 i1 = *(const float4*)(p + 65536);
            float4 i2 = *(const float4*)(p + 131072);
#pragma unroll
            for (int lvl = 13; lvl < 16; ++lvl) {
                float g = c_G[lvl];
                const float* T = tab + (size_t)lvl * 196608;
                uint32_t g0 = hash3(i0.x, i1.x, i2.x, g);
                uint32_t g1 = hash3(i0.y, i1.y, i2.y, g);
                uint32_t g2 = hash3(i0.z, i1.z, i2.z, g);
                uint32_t g3 = hash3(i0.w, i1.w, i2.w, g);
                float3 f0 = *(const float3*)(T + g0 * 3);
                float3 f1 = *(const float3*)(T + g1 * 3);
                float3 f2 = *(const float3*)(T + g2 * 3);
                float3 f3 = *(const float3*)(T + g3 * 3);
                float4 o0, o1, o2;
                o0.x = f0.x; o1.x = f0.y; o2.x = f0.z;
                o0.y = f1.x; o1.y = f1.y; o2.y = f1.z;
                o0.z = f2.x; o1.z = f2.y; o2.z = f2.z;
                o0.w = f3.x; o1.w = f3.y; o2.w = f3.z;
                float* ob = out + ((size_t)b * 48 + 3 * lvl) * 65536 + pix0;
                *(float4*)ob            = o0;
                *(float4*)(ob + 65536)  = o1;
                *(float4*)(ob + 131072) = o2;
            }
        } else {
            // ---- tile: levels 0..12, batch-major order ----
            float4* s = (float4*)smem;
            int tw   = (int)(w - POOL_WORKS - DIR_WORKS);   // 0..3327
            int b    = tw / 208;
            int r208 = tw - b * 208;
            int lvl  = r208 >> 4;
            int tile = r208 & 15;
            int P    = c_P[lvl];
            int yt0  = (tile >> 2) * 64;
            int xt0  = (tile & 3) * 64;

            // polite gate: relaxed poll + one acquire fence
            if (threadIdx.x == 0) {
                while (__hip_atomic_load(&bctr[b], __ATOMIC_RELAXED, __HIP_MEMORY_SCOPE_AGENT) < 32u)
                    __builtin_amdgcn_s_sleep(8);
                __builtin_amdgcn_fence(__ATOMIC_ACQUIRE, "agent");
            }
            __syncthreads();

            int nlo  = ((2 * yt0 + 1) * P - 256) >> 9;
            int r_lo = nlo < 0 ? 0 : (nlo > P - 1 ? P - 1 : nlo);
            int nhi  = (((2 * (yt0 + 63) + 1) * P - 256) >> 9) + 1;
            int r_hi = nhi < 0 ? 0 : (nhi > P - 1 ? P - 1 : nhi);
            int mlo  = ((2 * xt0 + 1) * P - 256) >> 9;
            int c_lo = mlo < 0 ? 0 : (mlo > P - 1 ? P - 1 : mlo);
            int mhi  = (((2 * (xt0 + 63) + 1) * P - 256) >> 9) + 1;
            int c_hi = mhi < 0 ? 0 : (mhi > P - 1 ? P - 1 : mhi);
            int span_y = r_hi - r_lo + 1;
            int span_x = c_hi - c_lo + 1;

            int planebase = c_CUM[lvl] * NB + b * P * P;
            const float* T = tab + (size_t)lvl * 196608;
            float gmul = c_G[lvl];
            int n = span_y * span_x;
            for (int t = threadIdx.x; t < n; t += 256) {
                int rr = t / span_x, cc = t - rr * span_x;
                int idx = planebase + (r_lo + rr) * P + c_lo + cc;
                float m0 = mws[idx];
                float m1 = mws[idx + CELLS_TOT];
                float m2 = mws[idx + 2 * CELLS_TOT];
                uint32_t g = hash3(m0, m1, m2, gmul);
                float3 tv = *(const float3*)(T + g * 3);
                float4 fv; fv.x = tv.x; fv.y = tv.y; fv.z = tv.z; fv.w = 0.f;
                s[t] = fv;
            }
            __syncthreads();

            int lane = threadIdx.x & 63;
            int wv   = threadIdx.x >> 6;
            int xq   = lane & 15;
            int rg   = lane >> 4;
            int xb   = xt0 + xq * 4;

            int ix0t[4], ix1t[4]; float wx0t[4], wx1t[4];
#pragma unroll
            for (int j = 0; j < 4; ++j) {
                int numx = (2 * (xb + j) + 1) * P - 256;
                int ix0  = numx >> 9;
                float fx = (float)(numx & 511) * (1.0f / 512.0f);
                int ix1;
                if (ix0 < 0)           { ix0 = 0;     ix1 = 0;     fx = 0.f; }
                else if (ix0 >= P - 1) { ix0 = P - 1; ix1 = P - 1; fx = 0.f; }
                else                   { ix1 = ix0 + 1; }
                ix0t[j] = ix0 - c_lo; ix1t[j] = ix1 - c_lo; wx1t[j] = fx; wx0t[j] = 1.f - fx;
            }

            int cur0 = -1, cur1 = -1;
            float r0v[3][4], r1v[3][4];

#pragma unroll
            for (int k = 0; k < 4; ++k) {
                int y = yt0 + wv * 16 + rg * 4 + k;
                int numy = (2 * y + 1) * P - 256;
                int iy0  = numy >> 9;
                float fy = (float)(numy & 511) * (1.0f / 512.0f);
                int iy1;
                if (iy0 < 0)           { iy0 = 0;     iy1 = 0;     fy = 0.f; }
                else if (iy0 >= P - 1) { iy0 = P - 1; iy1 = P - 1; fy = 0.f; }
                else                   { iy1 = iy0 + 1; }

                if (iy0 != cur0) {
                    if (iy0 == cur1) {
#pragma unroll
                        for (int j = 0; j < 4; ++j) {
                            r0v[0][j] = r1v[0][j]; r0v[1][j] = r1v[1][j]; r0v[2][j] = r1v[2][j];
                        }
                    } else {
                        const float4* p0 = s + (iy0 - r_lo) * span_x;
#pragma unroll
                        for (int j = 0; j < 4; ++j) {
                            float4 a = p0[ix0t[j]], qq = p0[ix1t[j]];
                            r0v[0][j] = wx0t[j] * a.x + wx1t[j] * qq.x;
                            r0v[1][j] = wx0t[j] * a.y + wx1t[j] * qq.y;
                            r0v[2][j] = wx0t[j] * a.z + wx1t[j] * qq.z;
                        }
                    }
                    cur0 = iy0;
                }
                if (iy1 != cur1) {
                    if (iy1 == cur0 && iy1 == iy0) {
#pragma unroll
                        for (int j = 0; j < 4; ++j) {
                            r1v[0][j] = r0v[0][j]; r1v[1][j] = r0v[1][j]; r1v[2][j] = r0v[2][j];
                        }
                    } else {
                        const float4* p1 = s + (iy1 - r_lo) * span_x;
#pragma unroll
                        for (int j = 0; j < 4; ++j) {
                            float4 a = p1[ix0t[j]], qq = p1[ix1t[j]];
                            r1v[0][j] = wx0t[j] * a.x + wx1t[j] * qq.x;
                            r1v[1][j] = wx0t[j] * a.y + wx1t[j] * qq.y;
                            r1v[2][j] = wx0t[j] * a.z + wx1t[j] * qq.z;
                        }
                    }
                    cur1 = iy1;
                }

                float wy1 = fy, wy0 = 1.f - fy;
                float* o = out + ((size_t)b * 48 + 3 * lvl) * 65536 + (size_t)y * 256 + xb;
#pragma unroll
                for (int c = 0; c < 3; ++c) {
                    float4 qv;
                    qv.x = wy0 * r0v[c][0] + wy1 * r1v[c][0];
                    qv.y = wy0 * r0v[c][1] + wy1 * r1v[c][1];
                    qv.z = wy0 * r0v[c][2] + wy1 * r1v[c][2];
                    qv.w = wy0 * r0v[c][3] + wy1 * r1v[c][3];
                    *(float4*)(o + (size_t)c * 65536) = qv;
                }
            }
        }
    }
}

extern "C" void kernel_launch(void* const* d_in, const int* in_sizes, int n_in,
                              void* d_out, int out_size, void* d_ws, size_t ws_size,
                              hipStream_t stream)
{
    const float* img = (const float*)d_in[0];   // (16,3,256,256) f32
    const float* tab = (const float*)d_in[1];   // (16,65536,3) f32
    float* out = (float*)d_out;                 // (16,48,256,256) f32
    float* mws = (float*)d_ws;                  // 6.4 MB maxima
    unsigned int* bctr = (unsigned int*)((char*)d_ws + (size_t)MWS_FLOATS * 4);

    (void)hipMemsetAsync(mws, 0, (size_t)MWS_FLOATS * 4, stream);   // straddle cells use atomicMax
    (void)hipMemsetAsync(bctr, 0, 64, stream);                      // 16 batch counters

    hipLaunchKernelGGL(mega, dim3(GRID_BLOCKS), dim3(256), 0, stream,
                       img, tab, mws, bctr, out);
}

// Round 23
// 75.190 us; speedup vs baseline: 5.4670x; 2.9084x over previous
//
#include <hip/hip_runtime.h>
#include <stdint.h>
#include <math.h>

// Multiresolution hash encoding, 16 levels.  (R16 structure + 2 micro-opts)
// grids = {4,5,6,9,12,15,21,27,36,48,63,84,111,147,194,255}
// kh = 256//grid, P = floor(256/kh).
// memset: mws = 0 (straddled cells use atomicMax; others plain-store).
// K1 fused: blocks [0,512)    = pooling levels 0..12 (8-row bands)
//           blocks [512,1536) = levels 13..15 direct (kh=1, identity bilinear)
// K2: LDS-tiled bilinear levels 0..12 (hash+gather fused into staging),
//     16 px/thread, cached x-interpolated row pair.
// All out writes: nontemporal float4 (write-once data; keep L2 for img/tab/mws).

#define NLVL 16
#define NB   16

typedef float nvec4 __attribute__((ext_vector_type(4)));

__constant__ int   c_P[NLVL]   = {4,5,6,9,12,15,21,28,36,51,64,85,128,256,256,256};
__constant__ float c_G[NLVL]   = {4.f,5.f,6.f,9.f,12.f,15.f,21.f,27.f,36.f,48.f,63.f,84.f,111.f,147.f,194.f,255.f};
__constant__ int   c_CUM[14]   = {0,16,41,77,158,302,527,968,1752,3048,5649,9745,16970,33354};

#define CELLS_PB   33354                 // cells/batch, levels 0..12
#define CELLS_TOT  (CELLS_PB*NB)         // 533664
#define MWS_FLOATS (CELLS_TOT*3)         // 1600992
#define POOL_BLOCKS (NB*32)              // 512: (batch, 8-row band)
#define DIR_BLOCKS  1024
#define K1_BLOCKS   (POOL_BLOCKS + DIR_BLOCKS)   // 1536
#define TILE_BLOCKS (13*16*16)           // 3328

__device__ __forceinline__ uint32_t hash3(float m0, float m1, float m2, float g) {
    uint32_t v0 = (uint32_t)(int)(m0 * g);
    uint32_t v1 = (uint32_t)(int)(m1 * g);
    uint32_t v2 = (uint32_t)(int)(m2 * g);
    return (v0 ^ (v1 * 2654435761u) ^ (v2 * 805459861u)) & 0xFFFFu;
}

__device__ __forceinline__ void nt_store(float* p, float a, float b, float c, float d) {
    nvec4 v; v.x = a; v.y = b; v.z = c; v.w = d;
    __builtin_nontemporal_store(v, (nvec4*)p);
}

// ---- K1: fused pooling (8-row bands, levels 0..12) + direct levels 13..15 ----
__global__ __launch_bounds__(256) void pool_direct(const float* __restrict__ img,
                                                   const float* __restrict__ tab,
                                                   unsigned int* __restrict__ mws,
                                                   float* __restrict__ out)
{
    static constexpr int K_P[13]   = {4,5,6,9,12,15,21,28,36,51,64,85,128};
    static constexpr int K_KH[13]  = {64,51,42,28,21,17,12,9,7,5,4,3,2};
    static constexpr int K_CUM[13] = {0,16,41,77,158,302,527,968,1752,3048,5649,9745,16970};

    __shared__ float simg[3][8][256];
    __shared__ float colbuf[3][256];

    if (blockIdx.x >= POOL_BLOCKS) {
        // direct path, levels 13..15: identity bilinear, 4 px/thread
        int t = (blockIdx.x - POOL_BLOCKS) * 256 + threadIdx.x;   // 262144 total
        int b = t >> 14;
        int pix0 = (t & 16383) << 2;
        const float* p = img + (size_t)b * 196608 + pix0;
        float4 i0 = *(const float4*)p;
        float4 i1 = *(const float4*)(p + 65536);
        float4 i2 = *(const float4*)(p + 131072);
#pragma unroll
        for (int lvl = 13; lvl < 16; ++lvl) {
            float g = c_G[lvl];
            const float* T = tab + (size_t)lvl * 196608;
            uint32_t g0 = hash3(i0.x, i1.x, i2.x, g);
            uint32_t g1 = hash3(i0.y, i1.y, i2.y, g);
            uint32_t g2 = hash3(i0.z, i1.z, i2.z, g);
            uint32_t g3 = hash3(i0.w, i1.w, i2.w, g);
            float3 f0 = *(const float3*)(T + g0 * 3);
            float3 f1 = *(const float3*)(T + g1 * 3);
            float3 f2 = *(const float3*)(T + g2 * 3);
            float3 f3 = *(const float3*)(T + g3 * 3);
            float* ob = out + ((size_t)b * 48 + 3 * lvl) * 65536 + pix0;
            nt_store(ob,           f0.x, f1.x, f2.x, f3.x);
            nt_store(ob + 65536,   f0.y, f1.y, f2.y, f3.y);
            nt_store(ob + 131072,  f0.z, f1.z, f2.z, f3.z);
        }
        return;
    }

    // pool path: 8-row band
    int b    = blockIdx.x >> 5;
    int band = blockIdx.x & 31;
    int y0   = band * 8;

    const float* base = img + (size_t)b * 196608 + (size_t)y0 * 256;
    for (int t = threadIdx.x; t < 1536; t += 256) {      // 1536 float4 = 3ch x 8rows x 256
        int ch = t >> 9;
        int r  = t & 511;
        float4 v = *(const float4*)(base + (size_t)ch * 65536 + r * 4);
        int row = r >> 6, c4 = (r & 63) << 2;
        simg[ch][row][c4 + 0] = v.x;
        simg[ch][row][c4 + 1] = v.y;
        simg[ch][row][c4 + 2] = v.z;
        simg[ch][row][c4 + 3] = v.w;
    }
    __syncthreads();

    int x = threadIdx.x;
#pragma unroll
    for (int lvl = 0; lvl < 13; ++lvl) {
        const int kh = K_KH[lvl], P = K_P[lvl];
        int nr0 = y0 / kh;
        int nr1 = (y0 + 7) / kh; if (nr1 > P - 1) nr1 = P - 1;
        for (int cr = nr0; cr <= nr1; ++cr) {
            int rlo = cr * kh;      if (rlo < y0) rlo = y0;
            int rhi = cr * kh + kh; if (rhi > y0 + 8) rhi = y0 + 8;
            float p0 = -INFINITY, p1 = -INFINITY, p2 = -INFINITY;
            for (int r = rlo; r < rhi; ++r) {
                int rr = r - y0;
                p0 = fmaxf(p0, simg[0][rr][x]);
                p1 = fmaxf(p1, simg[1][rr][x]);
                p2 = fmaxf(p2, simg[2][rr][x]);
            }
            colbuf[0][x] = p0; colbuf[1][x] = p1; colbuf[2][x] = p2;
            __syncthreads();
            if (x < P) {
                float q0 = -INFINITY, q1 = -INFINITY, q2 = -INFINITY;
                for (int c = x * kh; c < x * kh + kh; ++c) {
                    q0 = fmaxf(q0, colbuf[0][c]);
                    q1 = fmaxf(q1, colbuf[1][c]);
                    q2 = fmaxf(q2, colbuf[2][c]);
                }
                int idx = K_CUM[lvl] * NB + b * P * P + cr * P + x;
                if (rlo == cr * kh && rhi == cr * kh + kh) {
                    // band fully covers this cell-row: exclusive owner -> plain store
                    mws[idx]                 = __float_as_uint(q0);
                    mws[idx + CELLS_TOT]     = __float_as_uint(q1);
                    mws[idx + 2 * CELLS_TOT] = __float_as_uint(q2);
                } else {
                    atomicMax(&mws[idx],                 __float_as_uint(q0));
                    atomicMax(&mws[idx + CELLS_TOT],     __float_as_uint(q1));
                    atomicMax(&mws[idx + 2 * CELLS_TOT], __float_as_uint(q2));
                }
            }
            __syncthreads();
        }
    }
}

// ---- K2: LDS-tiled bilinear levels 0..12, cached x-interpolated row pair ----
// src = ((2o+1)*P - 256)/512 : exact int; frac exact in fp32.
__global__ __launch_bounds__(256) void render_tiles(const float* __restrict__ tab,
                                                    const float* __restrict__ mws,
                                                    float* __restrict__ out)
{
    __shared__ float4 s[34 * 34];
    int blk   = blockIdx.x;
    int tile  = blk & 15;
    int plane = blk >> 4;            // 0..207
    int lvl   = plane >> 4;
    int b     = plane & 15;
    int P     = c_P[lvl];
    int yt0   = (tile >> 2) * 64;
    int xt0   = (tile & 3) * 64;

    int nlo  = ((2 * yt0 + 1) * P - 256) >> 9;
    int r_lo = nlo < 0 ? 0 : (nlo > P - 1 ? P - 1 : nlo);
    int nhi  = (((2 * (yt0 + 63) + 1) * P - 256) >> 9) + 1;
    int r_hi = nhi < 0 ? 0 : (nhi > P - 1 ? P - 1 : nhi);
    int mlo  = ((2 * xt0 + 1) * P - 256) >> 9;
    int c_lo = mlo < 0 ? 0 : (mlo > P - 1 ? P - 1 : mlo);
    int mhi  = (((2 * (xt0 + 63) + 1) * P - 256) >> 9) + 1;
    int c_hi = mhi < 0 ? 0 : (mhi > P - 1 ? P - 1 : mhi);
    int span_y = r_hi - r_lo + 1;
    int span_x = c_hi - c_lo + 1;

    // stage: read maxima, hash, gather table feature per window cell
    int planebase = c_CUM[lvl] * NB + b * P * P;
    const float* T = tab + (size_t)lvl * 196608;
    float gmul = c_G[lvl];
    int n = span_y * span_x;
    for (int t = threadIdx.x; t < n; t += 256) {
        int r = t / span_x, c = t - r * span_x;
        int idx = planebase + (r_lo + r) * P + c_lo + c;
        float m0 = mws[idx];
        float m1 = mws[idx + CELLS_TOT];
        float m2 = mws[idx + 2 * CELLS_TOT];
        uint32_t g = hash3(m0, m1, m2, gmul);
        float3 tv = *(const float3*)(T + g * 3);
        float4 fv; fv.x = tv.x; fv.y = tv.y; fv.z = tv.z; fv.w = 0.f;
        s[t] = fv;
    }
    __syncthreads();

    int lane = threadIdx.x & 63;
    int w    = threadIdx.x >> 6;
    int xq   = lane & 15;
    int rg   = lane >> 4;
    int xb   = xt0 + xq * 4;

    int ix0t[4], ix1t[4]; float wx0t[4], wx1t[4];
#pragma unroll
    for (int j = 0; j < 4; ++j) {
        int numx = (2 * (xb + j) + 1) * P - 256;
        int ix0  = numx >> 9;
        float fx = (float)(numx & 511) * (1.0f / 512.0f);
        int ix1;
        if (ix0 < 0)           { ix0 = 0;     ix1 = 0;     fx = 0.f; }
        else if (ix0 >= P - 1) { ix0 = P - 1; ix1 = P - 1; fx = 0.f; }
        else                   { ix1 = ix0 + 1; }
        ix0t[j] = ix0 - c_lo; ix1t[j] = ix1 - c_lo; wx1t[j] = fx; wx0t[j] = 1.f - fx;
    }

    int cur0 = -1, cur1 = -1;
    float r0v[3][4], r1v[3][4];

#pragma unroll
    for (int k = 0; k < 4; ++k) {
        int y = yt0 + w * 16 + rg * 4 + k;
        int numy = (2 * y + 1) * P - 256;
        int iy0  = numy >> 9;
        float fy = (float)(numy & 511) * (1.0f / 512.0f);
        int iy1;
        if (iy0 < 0)           { iy0 = 0;     iy1 = 0;     fy = 0.f; }
        else if (iy0 >= P - 1) { iy0 = P - 1; iy1 = P - 1; fy = 0.f; }
        else                   { iy1 = iy0 + 1; }

        if (iy0 != cur0) {
            if (iy0 == cur1) {
#pragma unroll
                for (int j = 0; j < 4; ++j) {
                    r0v[0][j] = r1v[0][j]; r0v[1][j] = r1v[1][j]; r0v[2][j] = r1v[2][j];
                }
            } else {
                const float4* p0 = s + (iy0 - r_lo) * span_x;
#pragma unroll
                for (int j = 0; j < 4; ++j) {
                    float4 a = p0[ix0t[j]], q = p0[ix1t[j]];
                    r0v[0][j] = wx0t[j] * a.x + wx1t[j] * q.x;
                    r0v[1][j] = wx0t[j] * a.y + wx1t[j] * q.y;
                    r0v[2][j] = wx0t[j] * a.z + wx1t[j] * q.z;
                }
            }
            cur0 = iy0;
        }
        if (iy1 != cur1) {
            if (iy1 == cur0 && iy1 == iy0) {
#pragma unroll
                for (int j = 0; j < 4; ++j) {
                    r1v[0][j] = r0v[0][j]; r1v[1][j] = r0v[1][j]; r1v[2][j] = r0v[2][j];
                }
            } else {
                const float4* p1 = s + (iy1 - r_lo) * span_x;
#pragma unroll
                for (int j = 0; j < 4; ++j) {
                    float4 a = p1[ix0t[j]], q = p1[ix1t[j]];
                    r1v[0][j] = wx0t[j] * a.x + wx1t[j] * q.x;
                    r1v[1][j] = wx0t[j] * a.y + wx1t[j] * q.y;
                    r1v[2][j] = wx0t[j] * a.z + wx1t[j] * q.z;
                }
            }
            cur1 = iy1;
        }

        float wy1 = fy, wy0 = 1.f - fy;
        float* o = out + ((size_t)b * 48 + 3 * lvl) * 65536 + (size_t)y * 256 + xb;
#pragma unroll
        for (int c = 0; c < 3; ++c) {
            nt_store(o + (size_t)c * 65536,
                     wy0 * r0v[c][0] + wy1 * r1v[c][0],
                     wy0 * r0v[c][1] + wy1 * r1v[c][1],
                     wy0 * r0v[c][2] + wy1 * r1v[c][2],
                     wy0 * r0v[c][3] + wy1 * r1v[c][3]);
        }
    }
}

extern "C" void kernel_launch(void* const* d_in, const int* in_sizes, int n_in,
                              void* d_out, int out_size, void* d_ws, size_t ws_size,
                              hipStream_t stream)
{
    const float* img = (const float*)d_in[0];   // (16,3,256,256) f32
    const float* tab = (const float*)d_in[1];   // (16,65536,3) f32
    float* out = (float*)d_out;                 // (16,48,256,256) f32
    float* mws = (float*)d_ws;                  // 1,600,992 f32 = 6.4 MB

    (void)hipMemsetAsync(mws, 0, (size_t)MWS_FLOATS * sizeof(float), stream);
    hipLaunchKernelGGL(pool_direct,  dim3(K1_BLOCKS), dim3(256), 0, stream, img, tab, (unsigned int*)mws, out);
    hipLaunchKernelGGL(render_tiles, dim3(TILE_BLOCKS), dim3(256), 0, stream, tab, mws, out);
}